// Round 12
// baseline (107.673 us; speedup 1.0000x reference)
//
#include <hip/hip_runtime.h>
#include <math.h>
#include <stdint.h>

#define NB 8
#define P_TOTAL 13343
#define NCLS 80
#define KTOP 1000
#define PPAD 16384
#define D_SCORE_THR 0.05
#define D_IOU_THR 0.6

// ---------------- helpers ----------------

__device__ __forceinline__ double sig64(double x) {
    if (x >= 0.0) {
        double e = exp(-x);
        return 1.0 / (1.0 + e);
    } else {
        double e = exp(x);
        return e / (1.0 + e);
    }
}

// key = score bits (top 50) | (0x3FFF - idx): descending order => score desc, idx asc
__device__ __forceinline__ uint64_t pack_key(double s, int p) {
    uint64_t b = (uint64_t)__double_as_longlong(s);
    return (b & ~0x3FFFull) | (uint64_t)(0x3FFF - p);
}

__device__ __forceinline__ double key_score(uint64_t key) {
    return __longlong_as_double((long long)(key & ~0x3FFFull));
}

__device__ __forceinline__ int val_bin(double s) {
    int bin = (int)(s * 2048.0);
    return bin < 0 ? 0 : (bin > 2047 ? 2047 : bin);
}

__device__ __forceinline__ uint64_t rl64(uint64_t v, int l) {
    uint32_t lo = (uint32_t)__builtin_amdgcn_readlane((int)(uint32_t)v, l);
    uint32_t hi = (uint32_t)__builtin_amdgcn_readlane((int)(uint32_t)(v >> 32), l);
    return ((uint64_t)hi << 32) | lo;
}

// order-preserving double -> u64 encoding (for atomicMax)
__device__ __forceinline__ unsigned long long enc64(double x) {
    long long u = __double_as_longlong(x);
    return (unsigned long long)(u < 0 ? ~u : (u | 0x8000000000000000ll));
}
__device__ __forceinline__ double dec64(unsigned long long e) {
    long long u = (e >> 63) ? (long long)(e & 0x7FFFFFFFFFFFFFFFull) : ~(long long)e;
    return __longlong_as_double(u);
}

// ---------------- S0: scores/classes -> packed keys (+ zero tiny scratch) -------

__global__ __launch_bounds__(256) void k_scores(
    const float* __restrict__ c0, const float* __restrict__ c1, const float* __restrict__ c2,
    const float* __restrict__ c3, const float* __restrict__ c4,
    const float* __restrict__ n0, const float* __restrict__ n1, const float* __restrict__ n2,
    const float* __restrict__ n3, const float* __restrict__ n4,
    uint64_t* __restrict__ packed, int* __restrict__ classes,
    uint64_t* __restrict__ keepw, unsigned long long* __restrict__ pmaxE)
{
    int tid = threadIdx.x;
    if (blockIdx.x == 0) {
        if (tid < 128) keepw[tid] = 0ull;          // 8 batches x 16 words
        else if (tid < 136) pmaxE[tid - 128] = 0ull;
    }

    int gid = blockIdx.x * 256 + tid;
    if (gid >= NB * PPAD) return;
    int b = gid >> 14;
    int p = gid & (PPAD - 1);
    if (p >= P_TOTAL) { packed[gid] = 0; return; }

    int base, hw;
    const float* cls;
    const float* cnt;
    if (p < 10000)      { base = 0;     hw = 10000; cls = c0; cnt = n0; }
    else if (p < 12500) { base = 10000; hw = 2500;  cls = c1; cnt = n1; }
    else if (p < 13125) { base = 12500; hw = 625;   cls = c2; cnt = n2; }
    else if (p < 13294) { base = 13125; hw = 169;   cls = c3; cnt = n3; }
    else                { base = 13294; hw = 49;    cls = c4; cnt = n4; }
    int yx = p - base;

    // argmax over 80 logits; two 40-chains for ILP; first-max ties preserved.
    const float* cp = cls + (size_t)b * NCLS * hw + yx;
    float m0 = -3.4e38f, m1 = -3.4e38f;
    int a0 = 0, a1 = 40;
    for (int c = 0; c < 40; ++c) {
        float v0 = cp[(size_t)c * hw];
        float v1 = cp[(size_t)(c + 40) * hw];
        if (v0 > m0) { m0 = v0; a0 = c; }
        if (v1 > m1) { m1 = v1; a1 = c + 40; }
    }
    float m = m0; int am = a0;
    if (m1 > m0) { m = m1; am = a1; }

    float cv = cnt[(size_t)b * hw + yx];
    double s = sqrt(sig64((double)m) * sig64((double)cv));

    packed[gid] = pack_key(s, p);
    classes[(size_t)b * P_TOTAL + p] = am + 1;
}

// ---------------- S1: fused hist + threshold + STABLE compact + rank + gather ---
// 256 blocks (32 per batch), fully self-contained. Compaction is deterministic
// and stable (ballot record + LDS prefix scan, no atomics), so every block
// derives the IDENTICAL cand ordering -> block g's slot range [g*64, g*64+64)
// is a true partition of the candidate set. Rank (= #{ref > key}, keys unique)
// is a bijection onto the exact (score desc, idx asc) sorted order.

__global__ __launch_bounds__(256) void k_rankprep(
    const uint64_t* __restrict__ packed, const int* __restrict__ classes,
    const float* __restrict__ r0, const float* __restrict__ r1, const float* __restrict__ r2,
    const float* __restrict__ r3, const float* __restrict__ r4,
    double4* __restrict__ rawbox, float* __restrict__ clsall,
    float* __restrict__ outs, float* __restrict__ outc, float* __restrict__ outb,
    uint64_t* __restrict__ keepw, unsigned long long* __restrict__ pmaxE)
{
    __shared__ uint32_t lh[2048];
    __shared__ uint64_t cand[2048];
    __shared__ uint64_t balArr[256];   // [iter 0..63][wave 0..3] predicate ballots
    __shared__ uint32_t pfx[256];
    __shared__ uint32_t chs[64];
    __shared__ uint32_t ps[4][64];
    __shared__ int sB;
    int blk = blockIdx.x;
    int b = blk >> 5, g = blk & 31;
    int tid = threadIdx.x;
    int lane = tid & 63, wid = tid >> 6;
    const uint64_t* pk = packed + (size_t)b * PPAD;

    for (int t = tid; t < 2048; t += 256) { lh[t] = 0; cand[t] = 0; }
    __syncthreads();

    // pass 1: 2048-bin value histogram (deterministic counts)
    for (int t = tid; t < PPAD; t += 256)
        atomicAdd(&lh[val_bin(key_score(pk[t]))], 1u);
    __syncthreads();

    if (tid < 64) {
        uint32_t ss = 0;
        for (int i = 0; i < 32; ++i) ss += lh[tid * 32 + i];
        chs[tid] = ss;
    }
    __syncthreads();
    if (wid == 0) {
        // largest bin B with count(bin >= B) >= 1024 (suffix sums via scans)
        uint32_t v = chs[63 - lane];
        uint32_t P = v;
        for (int d = 1; d < 64; d <<= 1) {
            uint32_t u = __shfl_up(P, d, 64);
            if (lane >= d) P += u;
        }
        uint64_t bal = __ballot(P >= 1024u);
        int lstar = __builtin_ctzll(bal);
        int cstar = 63 - lstar;
        uint32_t Pst = (uint32_t)__shfl((int)P, lstar, 64);
        uint32_t C1c = Pst - chs[cstar];
        uint32_t w = (lane < 32) ? lh[cstar * 32 + 31 - lane] : 0u;
        uint32_t Q = w;
        for (int d = 1; d < 32; d <<= 1) {
            uint32_t u = __shfl_up(Q, d, 64);
            if (lane >= d) Q += u;
        }
        uint64_t bal2 = __ballot((lane < 32) && (C1c + Q >= 1024u));
        int l2 = __builtin_ctzll(bal2);
        if (lane == 0) sB = cstar * 32 + 31 - l2;
    }
    __syncthreads();
    int B = sB;

    // pass 2a: record predicate ballots (pure function of data -> identical
    // across blocks)
#pragma unroll 4
    for (int i = 0; i < 64; ++i) {
        int t = i * 256 + tid;
        bool pred = (val_bin(key_score(pk[t])) >= B);
        uint64_t bal = __ballot(pred);
        if (lane == 0) balArr[i * 4 + wid] = bal;
    }
    __syncthreads();

    // deterministic inclusive prefix scan over the 256 ballot popcounts
    uint32_t myc = (uint32_t)__popcll(balArr[tid]);
    pfx[tid] = myc;
    __syncthreads();
    for (int d = 1; d < 256; d <<= 1) {
        uint32_t add = (tid >= d) ? pfx[tid - d] : 0u;
        __syncthreads();
        pfx[tid] += add;
        __syncthreads();
    }

    // pass 2b: stable placement (slot = exclusive base of word + rank-in-word)
#pragma unroll 4
    for (int i = 0; i < 64; ++i) {
        int t = i * 256 + tid;
        int word = i * 4 + wid;
        uint64_t bal = balArr[word];
        bool pred = (bal >> lane) & 1ull;
        if (pred) {
            int slot = (int)(pfx[word] - __popcll(bal))
                     + __popcll(bal & ((1ull << lane) - 1ull));
            if (slot < 2048) cand[slot] = pk[t];
        }
    }
    __syncthreads();

    // rank this block's 64 keys against all 2048 (wave-uniform LDS broadcasts)
    uint64_t mykey = cand[g * 64 + lane];
    const uint64_t* ref = &cand[wid * 512];
    uint32_t rc = 0;
#pragma unroll 8
    for (int r = 0; r < 512; ++r) rc += (ref[r] > mykey) ? 1u : 0u;
    ps[wid][lane] = rc;
    __syncthreads();

    // gather + scatter-to-rank (one wave per block)
    if (tid < 64) {
        uint32_t rank = ps[0][tid] + ps[1][tid] + ps[2][tid] + ps[3][tid];
        uint64_t key = cand[g * 64 + tid];
        double lm = -1e300;
        if (key != 0ull && rank < 1024u) {
            int idx = 0x3FFF - (int)(key & 0x3FFF);
            idx = idx < 0 ? 0 : (idx > P_TOTAL - 1 ? P_TOTAL - 1 : idx);
            double s = key_score(key);

            int base2, w2, hw, st;
            const float* reg;
            if (idx < 10000)      { base2 = 0;     w2 = 100; hw = 10000; st = 8;   reg = r0; }
            else if (idx < 12500) { base2 = 10000; w2 = 50;  hw = 2500;  st = 16;  reg = r1; }
            else if (idx < 13125) { base2 = 12500; w2 = 25;  hw = 625;   st = 32;  reg = r2; }
            else if (idx < 13294) { base2 = 13125; w2 = 13;  hw = 169;   st = 64;  reg = r3; }
            else                  { base2 = 13294; w2 = 7;   hw = 49;    st = 128; reg = r4; }
            int yx = idx - base2;
            int y = yx / w2;
            int x = yx - y * w2;
            double sx = (double)(x * st + st / 2);
            double sy = (double)(y * st + st / 2);
            const float* rp = reg + (size_t)b * 4 * hw + yx;
            double x1 = sx - (double)rp[0];
            double y1 = sy - (double)rp[hw];
            double x2 = sx + (double)rp[2 * (size_t)hw];
            double y2 = sy + (double)rp[3 * (size_t)hw];
            int cv = classes[(size_t)b * P_TOTAL + idx];

            bool valid = (rank < KTOP) && (s >= D_SCORE_THR);
            size_t ix = (size_t)b * 1024 + rank;
            rawbox[ix] = make_double4(x1, y1, x2, y2);
            clsall[ix] = (float)cv;
            if (rank < KTOP) {
                outs[ix] = (float)s;
                outc[ix] = (float)cv;
                ((float4*)outb)[ix] = make_float4((float)x1, (float)y1,
                                                  (float)x2, (float)y2);
                // reference: max over where(valid, coords, 0.0)
                lm = valid ? fmax(fmax(x1, y1), fmax(x2, y2)) : 0.0;
            }
            if (valid)
                atomicOr((unsigned long long*)&keepw[(size_t)b * 16 + (rank >> 6)],
                         1ull << (rank & 63));
        }
        // wave fmax reduce (exact) -> one atomicMax per block
        for (int d = 1; d < 64; d <<= 1)
            lm = fmax(lm, __shfl_xor(lm, d, 64));
        if (tid == 0) atomicMax(&pmaxE[b], enc64(lm));
    }
}

// ---------------- S2: mask matrix from staged boxes (coalesced) -----------------

__global__ __launch_bounds__(256) void k_mask(
    const double4* __restrict__ rawbox, const float* __restrict__ clsall,
    const unsigned long long* __restrict__ pmaxE,
    uint64_t* __restrict__ M, uint64_t* __restrict__ D,
    uint32_t* __restrict__ Rnz)
{
    __shared__ double lx1[1024], ly1[1024], lx2[1024], ly2[1024], lar[1024];
    __shared__ float4 fbox[1024];
    __shared__ uint64_t ornz[4][64];
    int bid = blockIdx.x;
    int b = bid >> 4, rb = bid & 15;
    int tid = threadIdx.x;

    double offscale = dec64(pmaxE[b]) + 1.0;

    for (int t = tid; t < 1024; t += 256) {
        size_t ix = (size_t)b * 1024 + t;
        double4 rb4 = rawbox[ix];
        double o = (double)clsall[ix] * offscale;
        double ox1 = rb4.x + o, oy1 = rb4.y + o;
        double ox2 = rb4.z + o, oy2 = rb4.w + o;
        lx1[t] = ox1; ly1[t] = oy1; lx2[t] = ox2; ly2[t] = oy2;
        lar[t] = (ox2 - ox1 + 1.0) * (oy2 - oy1 + 1.0);
        fbox[t] = make_float4((float)ox1, (float)oy1, (float)ox2, (float)oy2);
    }
    __syncthreads();

    int ww = tid >> 6;
    int l  = tid & 63;
    int r  = rb * 64 + l;
    float4 fr = fbox[r];
    double rx1 = lx1[r], ry1 = ly1[r], rx2 = lx2[r], ry2 = ly2[r], ra = lar[r];
    int wbase = ww * 4;

    uint64_t bits0 = 0, bits1 = 0, bits2 = 0, bits3 = 0;

#define COLWORD(Q, BITS)                                                       \
    {                                                                          \
        int cb = (wbase + (Q)) * 64;                                           \
        if (cb + 63 > r) {                                                     \
            for (int kk = 0; kk < 64; ++kk) {                                  \
                int j = cb + kk;                                               \
                float4 fb = fbox[j];                                           \
                float xm = fminf(fb.z, fr.z) - fmaxf(fb.x, fr.x);              \
                float ym = fminf(fb.w, fr.w) - fmaxf(fb.y, fr.y);              \
                if (xm > -0.5f && ym > -0.5f) {                                \
                    double xmn = fmax(lx1[j], rx1);                            \
                    double ymn = fmax(ly1[j], ry1);                            \
                    double xmx = fmin(lx2[j], rx2);                            \
                    double ymx = fmin(ly2[j], ry2);                            \
                    double iw = xmx - xmn; iw = iw < 0.0 ? 0.0 : iw;           \
                    double ih = ymx - ymn; ih = ih < 0.0 ? 0.0 : ih;           \
                    double inter = iw * ih;                                    \
                    double iou = inter / (ra + lar[j] - inter);                \
                    BITS |= ((uint64_t)((j > r) && (iou > D_IOU_THR))) << kk;  \
                }                                                              \
            }                                                                  \
        }                                                                      \
    }

    COLWORD(0, bits0) COLWORD(1, bits1) COLWORD(2, bits2) COLWORD(3, bits3)
#undef COLWORD

    size_t mrow = ((size_t)b * 1024 + r) * 16 + wbase;
    M[mrow + 0] = bits0; M[mrow + 1] = bits1;
    M[mrow + 2] = bits2; M[mrow + 3] = bits3;

    if (ww == (rb >> 2)) {
        uint64_t db = (rb & 3) == 0 ? bits0 : (rb & 3) == 1 ? bits1
                    : (rb & 3) == 2 ? bits2 : bits3;
        D[((size_t)b * 16 + rb) * 64 + l] = db;
    }

    ornz[ww][l] = bits0 | bits1 | bits2 | bits3;
    __syncthreads();
    if (ww == 0) {
        uint64_t o = ornz[0][l] | ornz[1][l] | ornz[2][l] | ornz[3][l];
        Rnz[(size_t)b * 1024 + r] = (o != 0) ? 1u : 0u;
    }
}

// ---------------- S3: one-wave sparse scan ----------------

#define LOADC(G)                                                               \
    C0  = Mb[((size_t)(G) * 64 +  0 + p) * 16 + w];                            \
    C1  = Mb[((size_t)(G) * 64 +  4 + p) * 16 + w];                            \
    C2  = Mb[((size_t)(G) * 64 +  8 + p) * 16 + w];                            \
    C3  = Mb[((size_t)(G) * 64 + 12 + p) * 16 + w];                            \
    C4  = Mb[((size_t)(G) * 64 + 16 + p) * 16 + w];                            \
    C5  = Mb[((size_t)(G) * 64 + 20 + p) * 16 + w];                            \
    C6  = Mb[((size_t)(G) * 64 + 24 + p) * 16 + w];                            \
    C7  = Mb[((size_t)(G) * 64 + 28 + p) * 16 + w];                            \
    C8  = Mb[((size_t)(G) * 64 + 32 + p) * 16 + w];                            \
    C9  = Mb[((size_t)(G) * 64 + 36 + p) * 16 + w];                            \
    C10 = Mb[((size_t)(G) * 64 + 40 + p) * 16 + w];                            \
    C11 = Mb[((size_t)(G) * 64 + 44 + p) * 16 + w];                            \
    C12 = Mb[((size_t)(G) * 64 + 48 + p) * 16 + w];                            \
    C13 = Mb[((size_t)(G) * 64 + 52 + p) * 16 + w];                            \
    C14 = Mb[((size_t)(G) * 64 + 56 + p) * 16 + w];                            \
    C15 = Mb[((size_t)(G) * 64 + 60 + p) * 16 + w];

#define APPLY_Q(q)                                                             \
    {                                                                          \
        uint64_t t_ = (alive >> (4 * (q) + p)) & 1ull;                         \
        acc &= ~(C##q & (0ull - t_));                                          \
    }

#define STEPG(G)                                                               \
    {                                                                          \
        uint64_t kg = rl64(kw, (G));                                           \
        if (kg & nz##G) {                                                      \
            uint64_t dg = Dp[(size_t)(G) * 64 + lane];                         \
            LOADC(G)                                                           \
            uint64_t cur = kg, it = kg & nz##G;                                \
            while (it) {                                                       \
                int kk = __builtin_ctzll(it);                                  \
                uint64_t dk = rl64(dg, kk);                                    \
                cur &= ~dk;                                                    \
                it &= ~dk;                                                     \
                it &= it - 1ull;                                               \
            }                                                                  \
            uint64_t alive = cur;                                              \
            uint64_t acc = ~0ull;                                              \
            APPLY_Q(0)  APPLY_Q(1)  APPLY_Q(2)  APPLY_Q(3)                     \
            APPLY_Q(4)  APPLY_Q(5)  APPLY_Q(6)  APPLY_Q(7)                     \
            APPLY_Q(8)  APPLY_Q(9)  APPLY_Q(10) APPLY_Q(11)                    \
            APPLY_Q(12) APPLY_Q(13) APPLY_Q(14) APPLY_Q(15)                    \
            acc &= __shfl_xor(acc, 16, 64);                                    \
            acc &= __shfl_xor(acc, 32, 64);                                    \
            kw &= acc;                                                         \
        }                                                                      \
    }

__global__ __launch_bounds__(64, 1) void k_scan(
    const uint64_t* __restrict__ M, const uint64_t* __restrict__ D,
    const uint32_t* __restrict__ Rnz, const uint64_t* __restrict__ keepw,
    const float* __restrict__ outs, const float* __restrict__ outc,
    const float* __restrict__ outb, float* __restrict__ out)
{
    int b = blockIdx.x;
    int lane = threadIdx.x;          // one wave
    int p = (lane >> 4) & 3;         // replica 0..3
    int w = lane & 15;               // word index
    const uint64_t* Mb = M + (size_t)b * 1024 * 16;
    const uint64_t* Dp = D + (size_t)b * 1024;
    const uint32_t* Rp = Rnz + (size_t)b * 1024;

    uint64_t kw = keepw[(size_t)b * 16 + w];   // word w, replicated x4

    uint32_t f0  = Rp[0 * 64 + lane],  f1  = Rp[1 * 64 + lane];
    uint32_t f2  = Rp[2 * 64 + lane],  f3  = Rp[3 * 64 + lane];
    uint32_t f4  = Rp[4 * 64 + lane],  f5  = Rp[5 * 64 + lane];
    uint32_t f6  = Rp[6 * 64 + lane],  f7  = Rp[7 * 64 + lane];
    uint32_t f8  = Rp[8 * 64 + lane],  f9  = Rp[9 * 64 + lane];
    uint32_t f10 = Rp[10 * 64 + lane], f11 = Rp[11 * 64 + lane];
    uint32_t f12 = Rp[12 * 64 + lane], f13 = Rp[13 * 64 + lane];
    uint32_t f14 = Rp[14 * 64 + lane], f15 = Rp[15 * 64 + lane];
    uint64_t nz0  = __ballot(f0 != 0),  nz1  = __ballot(f1 != 0);
    uint64_t nz2  = __ballot(f2 != 0),  nz3  = __ballot(f3 != 0);
    uint64_t nz4  = __ballot(f4 != 0),  nz5  = __ballot(f5 != 0);
    uint64_t nz6  = __ballot(f6 != 0),  nz7  = __ballot(f7 != 0);
    uint64_t nz8  = __ballot(f8 != 0),  nz9  = __ballot(f9 != 0);
    uint64_t nz10 = __ballot(f10 != 0), nz11 = __ballot(f11 != 0);
    uint64_t nz12 = __ballot(f12 != 0), nz13 = __ballot(f13 != 0);
    uint64_t nz14 = __ballot(f14 != 0), nz15 = __ballot(f15 != 0);

    uint64_t C0,C1,C2,C3,C4,C5,C6,C7,C8,C9,C10,C11,C12,C13,C14,C15;

    STEPG(0)  STEPG(1)  STEPG(2)  STEPG(3)
    STEPG(4)  STEPG(5)  STEPG(6)  STEPG(7)
    STEPG(8)  STEPG(9)  STEPG(10) STEPG(11)
    STEPG(12) STEPG(13) STEPG(14) STEPG(15)

#pragma unroll
    for (int t = 0; t < 16; ++t) {
        int j = t * 64 + lane;
        uint64_t kwt = rl64(kw, t);
        bool kp = (kwt >> lane) & 1ull;
        if (j < KTOP) {
            size_t ix = (size_t)b * 1024 + j;
            out[(size_t)b * KTOP + j] = kp ? outs[ix] : 0.0f;
            out[(size_t)NB * KTOP + (size_t)b * KTOP + j] = kp ? outc[ix] : 0.0f;
            float4 bb = kp ? ((const float4*)outb)[ix] : make_float4(0.f, 0.f, 0.f, 0.f);
            ((float4*)(out + 2 * (size_t)NB * KTOP))[(size_t)b * KTOP + j] = bb;
        }
    }
}

// ---------------- launch ----------------

extern "C" void kernel_launch(void* const* d_in, const int* in_sizes, int n_in,
                              void* d_out, int out_size, void* d_ws, size_t ws_size,
                              hipStream_t stream) {
    const float* cls[5];
    const float* cnt[5];
    const float* reg[5];
    for (int i = 0; i < 5; ++i) {
        cls[i] = (const float*)d_in[i];
        cnt[i] = (const float*)d_in[5 + i];
        reg[i] = (const float*)d_in[10 + i];
    }
    float* out = (float*)d_out;

    // ws layout (bytes); M reuses the packed region (packed dead after k_rankprep)
    char* ws = (char*)d_ws;
    uint64_t* packed  = (uint64_t*)(ws + 0);          // 8*16384*8   = 1,048,576
    uint64_t* M       = (uint64_t*)(ws + 0);          // 8*1024*16*8 = 1,048,576 (reuse)
    int*      classes = (int*)     (ws + 1048576);    // 426,976
    double4*  rawbox  = (double4*) (ws + 1475552);    // 8*1024*32 = 262,144 (32B aligned)
    float*    clsall  = (float*)   (ws + 1737696);    // 32,768
    unsigned long long* pmaxE = (unsigned long long*)(ws + 1770464);  // 64
    uint64_t* keepw   = (uint64_t*)(ws + 1770528);    // 1,024
    uint64_t* D       = (uint64_t*)(ws + 1771552);    // 65,536
    uint32_t* Rnz     = (uint32_t*)(ws + 1837088);    // 32,768
    float*    outs    = (float*)   (ws + 1869856);    // 32,768
    float*    outc    = (float*)   (ws + 1902624);    // 32,768
    float*    outb    = (float*)   (ws + 1935392);    // 131,072 (16B aligned)

    k_scores<<<(NB * PPAD) / 256, 256, 0, stream>>>(
        cls[0], cls[1], cls[2], cls[3], cls[4],
        cnt[0], cnt[1], cnt[2], cnt[3], cnt[4],
        packed, classes, keepw, pmaxE);

    k_rankprep<<<NB * 32, 256, 0, stream>>>(packed, classes,
                                            reg[0], reg[1], reg[2], reg[3], reg[4],
                                            rawbox, clsall, outs, outc, outb,
                                            keepw, pmaxE);

    k_mask<<<NB * 16, 256, 0, stream>>>(rawbox, clsall, pmaxE, M, D, Rnz);

    k_scan<<<NB, 64, 0, stream>>>(M, D, Rnz, keepw, outs, outc, outb, out);
}

// Round 13
// 107.486 us; speedup vs baseline: 1.0017x; 1.0017x over previous
//
#include <hip/hip_runtime.h>
#include <math.h>
#include <stdint.h>

#define NB 8
#define P_TOTAL 13343
#define NCLS 80
#define KTOP 1000
#define PPAD 16384
#define D_SCORE_THR 0.05
#define D_IOU_THR 0.6

// ---------------- helpers ----------------

__device__ __forceinline__ double sig64(double x) {
    if (x >= 0.0) {
        double e = exp(-x);
        return 1.0 / (1.0 + e);
    } else {
        double e = exp(x);
        return e / (1.0 + e);
    }
}

// key = score bits (top 50) | (0x3FFF - idx): descending order => score desc, idx asc
__device__ __forceinline__ uint64_t pack_key(double s, int p) {
    uint64_t b = (uint64_t)__double_as_longlong(s);
    return (b & ~0x3FFFull) | (uint64_t)(0x3FFF - p);
}

__device__ __forceinline__ double key_score(uint64_t key) {
    return __longlong_as_double((long long)(key & ~0x3FFFull));
}

__device__ __forceinline__ int val_bin(double s) {
    int bin = (int)(s * 2048.0);
    return bin < 0 ? 0 : (bin > 2047 ? 2047 : bin);
}

__device__ __forceinline__ uint64_t rl64(uint64_t v, int l) {
    uint32_t lo = (uint32_t)__builtin_amdgcn_readlane((int)(uint32_t)v, l);
    uint32_t hi = (uint32_t)__builtin_amdgcn_readlane((int)(uint32_t)(v >> 32), l);
    return ((uint64_t)hi << 32) | lo;
}

// order-preserving double -> u64 encoding (for atomicMax)
__device__ __forceinline__ unsigned long long enc64(double x) {
    long long u = __double_as_longlong(x);
    return (unsigned long long)(u < 0 ? ~u : (u | 0x8000000000000000ll));
}
__device__ __forceinline__ double dec64(unsigned long long e) {
    long long u = (e >> 63) ? (long long)(e & 0x7FFFFFFFFFFFFFFFull) : ~(long long)e;
    return __longlong_as_double(u);
}

// ---------------- S0: scores/classes -> packed keys + global histogram ----------

__global__ __launch_bounds__(256) void k_scores(
    const float* __restrict__ c0, const float* __restrict__ c1, const float* __restrict__ c2,
    const float* __restrict__ c3, const float* __restrict__ c4,
    const float* __restrict__ n0, const float* __restrict__ n1, const float* __restrict__ n2,
    const float* __restrict__ n3, const float* __restrict__ n4,
    uint64_t* __restrict__ packed, int* __restrict__ classes,
    uint32_t* __restrict__ ghist,
    uint64_t* __restrict__ keepw, unsigned long long* __restrict__ pmaxE)
{
    int tid = threadIdx.x;
    if (blockIdx.x == 0) {
        if (tid < 128) keepw[tid] = 0ull;          // written later by k_rankprep only
        else if (tid < 136) pmaxE[tid - 128] = 0ull;
    }

    int gid = blockIdx.x * 256 + tid;
    if (gid >= NB * PPAD) return;
    int b = gid >> 14;
    int p = gid & (PPAD - 1);
    if (p >= P_TOTAL) { packed[gid] = 0; return; }

    int base, hw;
    const float* cls;
    const float* cnt;
    if (p < 10000)      { base = 0;     hw = 10000; cls = c0; cnt = n0; }
    else if (p < 12500) { base = 10000; hw = 2500;  cls = c1; cnt = n1; }
    else if (p < 13125) { base = 12500; hw = 625;   cls = c2; cnt = n2; }
    else if (p < 13294) { base = 13125; hw = 169;   cls = c3; cnt = n3; }
    else                { base = 13294; hw = 49;    cls = c4; cnt = n4; }
    int yx = p - base;

    // argmax over 80 logits; two 40-chains for ILP; first-max ties preserved.
    const float* cp = cls + (size_t)b * NCLS * hw + yx;
    float m0 = -3.4e38f, m1 = -3.4e38f;
    int a0 = 0, a1 = 40;
    for (int c = 0; c < 40; ++c) {
        float v0 = cp[(size_t)c * hw];
        float v1 = cp[(size_t)(c + 40) * hw];
        if (v0 > m0) { m0 = v0; a0 = c; }
        if (v1 > m1) { m1 = v1; a1 = c + 40; }
    }
    float m = m0; int am = a0;
    if (m1 > m0) { m = m1; am = a1; }

    float cv = cnt[(size_t)b * hw + yx];
    double s = sqrt(sig64((double)m) * sig64((double)cv));

    packed[gid] = pack_key(s, p);
    classes[(size_t)b * P_TOTAL + p] = am + 1;
    atomicAdd(&ghist[b * 2048 + val_bin(s)], 1u);   // ghist pre-zeroed via memsetAsync
}

// ---------------- S1: rank-scatter select+prep (source-range partition) ---------
// 256 blocks (32/batch). Responsibility = source range (intrinsic partition, no
// shared ordering needed). cand = candidate SET in any order (rank counting is
// order-invariant). rank(k) = #{cand > k} = #{all keys > k} (bins key-monotone),
// bijective since keys unique -> exact sorted order, every rank written once.

__global__ __launch_bounds__(256) void k_rankprep(
    const uint64_t* __restrict__ packed, const uint32_t* __restrict__ ghist,
    const int* __restrict__ classes,
    const float* __restrict__ r0, const float* __restrict__ r1, const float* __restrict__ r2,
    const float* __restrict__ r3, const float* __restrict__ r4,
    double4* __restrict__ rawbox, float* __restrict__ clsall,
    float* __restrict__ outs, float* __restrict__ outc, float* __restrict__ outb,
    uint64_t* __restrict__ keepw, unsigned long long* __restrict__ pmaxE)
{
    __shared__ uint32_t lh[2048];
    __shared__ uint64_t cand[2048];
    __shared__ uint64_t pass[512];
    __shared__ uint32_t chs[64];
    __shared__ uint32_t pcnt[4][64];
    __shared__ int sB, sCnt, sNP;
    int blk = blockIdx.x;
    int b = blk >> 5, g = blk & 31;
    int tid = threadIdx.x;
    int lane = tid & 63, wid = tid >> 6;
    const uint64_t* pk = packed + (size_t)b * PPAD;

    for (int t = tid; t < 2048; t += 256) { lh[t] = ghist[b * 2048 + t]; cand[t] = 0; }
    if (tid == 0) { sCnt = 0; sNP = 0; }
    __syncthreads();

    if (tid < 64) {
        uint32_t ss = 0;
        for (int i = 0; i < 32; ++i) ss += lh[tid * 32 + i];
        chs[tid] = ss;
    }
    __syncthreads();
    if (wid == 0) {
        // largest bin B with count(bin >= B) >= 1024 (suffix sums via scans)
        uint32_t v = chs[63 - lane];
        uint32_t P = v;
        for (int d = 1; d < 64; d <<= 1) {
            uint32_t u = __shfl_up(P, d, 64);
            if (lane >= d) P += u;
        }
        uint64_t bal = __ballot(P >= 1024u);
        int lstar = __builtin_ctzll(bal);
        int cstar = 63 - lstar;
        uint32_t Pst = (uint32_t)__shfl((int)P, lstar, 64);
        uint32_t C1c = Pst - chs[cstar];
        uint32_t w = (lane < 32) ? lh[cstar * 32 + 31 - lane] : 0u;
        uint32_t Q = w;
        for (int d = 1; d < 32; d <<= 1) {
            uint32_t u = __shfl_up(Q, d, 64);
            if (lane >= d) Q += u;
        }
        uint64_t bal2 = __ballot((lane < 32) && (C1c + Q >= 1024u));
        int l2 = __builtin_ctzll(bal2);
        if (lane == 0) sB = cstar * 32 + 31 - l2;
    }
    __syncthreads();
    int B = sB;

    // single pass: compact candidate SET (order-free) into LDS
    for (int t = tid; t < PPAD; t += 256) {
        uint64_t key = pk[t];
        bool pred = (val_bin(key_score(key)) >= B);
        uint64_t bal = __ballot(pred);
        int bs = 0;
        if (lane == 0 && bal) bs = atomicAdd(&sCnt, (int)__popcll(bal));
        bs = __shfl(bs, 0, 64);
        if (pred) {
            int s = bs + __popcll(bal & ((1ull << lane) - 1ull));
            if (s < 2048) cand[s] = key;
        }
    }

    // my slice's passers (responsibility set)
    int src0 = g * 512;
#pragma unroll
    for (int k = 0; k < 2; ++k) {
        uint64_t key = pk[src0 + tid + k * 256];
        bool pred = (val_bin(key_score(key)) >= B);
        uint64_t bal = __ballot(pred);
        int bs = 0;
        if (lane == 0 && bal) bs = atomicAdd(&sNP, (int)__popcll(bal));
        bs = __shfl(bs, 0, 64);
        if (pred) pass[bs + __popcll(bal & ((1ull << lane) - 1ull))] = key;
    }
    __syncthreads();
    int np = sNP;

    double lm = -1e300;
    for (int g0 = 0; g0 < np; g0 += 64) {
        bool have = (g0 + lane) < np;
        uint64_t mykey = have ? pass[g0 + lane] : ~0ull;   // sentinel: rank 0, gated by have
        uint32_t cnt = 0;
        const uint64_t* ref = &cand[wid * 512];
#pragma unroll 8
        for (int r = 0; r < 512; ++r) cnt += (ref[r] > mykey) ? 1u : 0u;
        pcnt[wid][lane] = cnt;
        __syncthreads();

        if (tid < 64) {
            bool hv = (g0 + tid) < np;
            uint32_t rank = pcnt[0][tid] + pcnt[1][tid] + pcnt[2][tid] + pcnt[3][tid];
            uint64_t key = hv ? pass[g0 + tid] : 0ull;
            if (hv && rank < 1024u) {
                int idx = 0x3FFF - (int)(key & 0x3FFF);
                idx = idx < 0 ? 0 : (idx > P_TOTAL - 1 ? P_TOTAL - 1 : idx);
                double s = key_score(key);

                int base2, w2, hw, st;
                const float* reg;
                if (idx < 10000)      { base2 = 0;     w2 = 100; hw = 10000; st = 8;   reg = r0; }
                else if (idx < 12500) { base2 = 10000; w2 = 50;  hw = 2500;  st = 16;  reg = r1; }
                else if (idx < 13125) { base2 = 12500; w2 = 25;  hw = 625;   st = 32;  reg = r2; }
                else if (idx < 13294) { base2 = 13125; w2 = 13;  hw = 169;   st = 64;  reg = r3; }
                else                  { base2 = 13294; w2 = 7;   hw = 49;    st = 128; reg = r4; }
                int yx = idx - base2;
                int y = yx / w2;
                int x = yx - y * w2;
                double sx = (double)(x * st + st / 2);
                double sy = (double)(y * st + st / 2);
                const float* rp = reg + (size_t)b * 4 * hw + yx;
                double x1 = sx - (double)rp[0];
                double y1 = sy - (double)rp[hw];
                double x2 = sx + (double)rp[2 * (size_t)hw];
                double y2 = sy + (double)rp[3 * (size_t)hw];
                int cv = classes[(size_t)b * P_TOTAL + idx];

                bool valid = (rank < KTOP) && (s >= D_SCORE_THR);
                size_t ix = (size_t)b * 1024 + rank;
                rawbox[ix] = make_double4(x1, y1, x2, y2);
                clsall[ix] = (float)cv;
                if (rank < KTOP) {
                    outs[ix] = (float)s;
                    outc[ix] = (float)cv;
                    ((float4*)outb)[ix] = make_float4((float)x1, (float)y1,
                                                      (float)x2, (float)y2);
                    // reference: max over where(valid, coords, 0.0)
                    lm = fmax(lm, valid ? fmax(fmax(x1, y1), fmax(x2, y2)) : 0.0);
                }
                if (valid)
                    atomicOr((unsigned long long*)&keepw[(size_t)b * 16 + (rank >> 6)],
                             1ull << (rank & 63));
            }
        }
        __syncthreads();
    }

    // wave-0 fmax reduce (exact) -> one atomicMax per block
    if (tid < 64) {
        for (int d = 1; d < 64; d <<= 1)
            lm = fmax(lm, __shfl_xor(lm, d, 64));
        if (tid == 0) atomicMax(&pmaxE[b], enc64(lm));
    }
}

// ---------------- S2: mask matrix from staged boxes (coalesced) -----------------

__global__ __launch_bounds__(256) void k_mask(
    const double4* __restrict__ rawbox, const float* __restrict__ clsall,
    const unsigned long long* __restrict__ pmaxE,
    uint64_t* __restrict__ M, uint64_t* __restrict__ D,
    uint32_t* __restrict__ Rnz)
{
    __shared__ double lx1[1024], ly1[1024], lx2[1024], ly2[1024], lar[1024];
    __shared__ float4 fbox[1024];
    __shared__ uint64_t ornz[4][64];
    int bid = blockIdx.x;
    int b = bid >> 4, rb = bid & 15;
    int tid = threadIdx.x;

    double offscale = dec64(pmaxE[b]) + 1.0;

    for (int t = tid; t < 1024; t += 256) {
        size_t ix = (size_t)b * 1024 + t;
        double4 rb4 = rawbox[ix];
        double o = (double)clsall[ix] * offscale;
        double ox1 = rb4.x + o, oy1 = rb4.y + o;
        double ox2 = rb4.z + o, oy2 = rb4.w + o;
        lx1[t] = ox1; ly1[t] = oy1; lx2[t] = ox2; ly2[t] = oy2;
        lar[t] = (ox2 - ox1 + 1.0) * (oy2 - oy1 + 1.0);
        fbox[t] = make_float4((float)ox1, (float)oy1, (float)ox2, (float)oy2);
    }
    __syncthreads();

    int ww = tid >> 6;
    int l  = tid & 63;
    int r  = rb * 64 + l;
    float4 fr = fbox[r];
    double rx1 = lx1[r], ry1 = ly1[r], rx2 = lx2[r], ry2 = ly2[r], ra = lar[r];
    int wbase = ww * 4;

    uint64_t bits0 = 0, bits1 = 0, bits2 = 0, bits3 = 0;

#define COLWORD(Q, BITS)                                                       \
    {                                                                          \
        int cb = (wbase + (Q)) * 64;                                           \
        if (cb + 63 > r) {                                                     \
            for (int kk = 0; kk < 64; ++kk) {                                  \
                int j = cb + kk;                                               \
                float4 fb = fbox[j];                                           \
                float xm = fminf(fb.z, fr.z) - fmaxf(fb.x, fr.x);              \
                float ym = fminf(fb.w, fr.w) - fmaxf(fb.y, fr.y);              \
                if (xm > -0.5f && ym > -0.5f) {                                \
                    double xmn = fmax(lx1[j], rx1);                            \
                    double ymn = fmax(ly1[j], ry1);                            \
                    double xmx = fmin(lx2[j], rx2);                            \
                    double ymx = fmin(ly2[j], ry2);                            \
                    double iw = xmx - xmn; iw = iw < 0.0 ? 0.0 : iw;           \
                    double ih = ymx - ymn; ih = ih < 0.0 ? 0.0 : ih;           \
                    double inter = iw * ih;                                    \
                    double iou = inter / (ra + lar[j] - inter);                \
                    BITS |= ((uint64_t)((j > r) && (iou > D_IOU_THR))) << kk;  \
                }                                                              \
            }                                                                  \
        }                                                                      \
    }

    COLWORD(0, bits0) COLWORD(1, bits1) COLWORD(2, bits2) COLWORD(3, bits3)
#undef COLWORD

    size_t mrow = ((size_t)b * 1024 + r) * 16 + wbase;
    M[mrow + 0] = bits0; M[mrow + 1] = bits1;
    M[mrow + 2] = bits2; M[mrow + 3] = bits3;

    if (ww == (rb >> 2)) {
        uint64_t db = (rb & 3) == 0 ? bits0 : (rb & 3) == 1 ? bits1
                    : (rb & 3) == 2 ? bits2 : bits3;
        D[((size_t)b * 16 + rb) * 64 + l] = db;
    }

    ornz[ww][l] = bits0 | bits1 | bits2 | bits3;
    __syncthreads();
    if (ww == 0) {
        uint64_t o = ornz[0][l] | ornz[1][l] | ornz[2][l] | ornz[3][l];
        Rnz[(size_t)b * 1024 + r] = (o != 0) ? 1u : 0u;
    }
}

// ---------------- S3: one-wave sparse scan ----------------

#define LOADC(G)                                                               \
    C0  = Mb[((size_t)(G) * 64 +  0 + p) * 16 + w];                            \
    C1  = Mb[((size_t)(G) * 64 +  4 + p) * 16 + w];                            \
    C2  = Mb[((size_t)(G) * 64 +  8 + p) * 16 + w];                            \
    C3  = Mb[((size_t)(G) * 64 + 12 + p) * 16 + w];                            \
    C4  = Mb[((size_t)(G) * 64 + 16 + p) * 16 + w];                            \
    C5  = Mb[((size_t)(G) * 64 + 20 + p) * 16 + w];                            \
    C6  = Mb[((size_t)(G) * 64 + 24 + p) * 16 + w];                            \
    C7  = Mb[((size_t)(G) * 64 + 28 + p) * 16 + w];                            \
    C8  = Mb[((size_t)(G) * 64 + 32 + p) * 16 + w];                            \
    C9  = Mb[((size_t)(G) * 64 + 36 + p) * 16 + w];                            \
    C10 = Mb[((size_t)(G) * 64 + 40 + p) * 16 + w];                            \
    C11 = Mb[((size_t)(G) * 64 + 44 + p) * 16 + w];                            \
    C12 = Mb[((size_t)(G) * 64 + 48 + p) * 16 + w];                            \
    C13 = Mb[((size_t)(G) * 64 + 52 + p) * 16 + w];                            \
    C14 = Mb[((size_t)(G) * 64 + 56 + p) * 16 + w];                            \
    C15 = Mb[((size_t)(G) * 64 + 60 + p) * 16 + w];

#define APPLY_Q(q)                                                             \
    {                                                                          \
        uint64_t t_ = (alive >> (4 * (q) + p)) & 1ull;                         \
        acc &= ~(C##q & (0ull - t_));                                          \
    }

#define STEPG(G)                                                               \
    {                                                                          \
        uint64_t kg = rl64(kw, (G));                                           \
        if (kg & nz##G) {                                                      \
            uint64_t dg = Dp[(size_t)(G) * 64 + lane];                         \
            LOADC(G)                                                           \
            uint64_t cur = kg, it = kg & nz##G;                                \
            while (it) {                                                       \
                int kk = __builtin_ctzll(it);                                  \
                uint64_t dk = rl64(dg, kk);                                    \
                cur &= ~dk;                                                    \
                it &= ~dk;                                                     \
                it &= it - 1ull;                                               \
            }                                                                  \
            uint64_t alive = cur;                                              \
            uint64_t acc = ~0ull;                                              \
            APPLY_Q(0)  APPLY_Q(1)  APPLY_Q(2)  APPLY_Q(3)                     \
            APPLY_Q(4)  APPLY_Q(5)  APPLY_Q(6)  APPLY_Q(7)                     \
            APPLY_Q(8)  APPLY_Q(9)  APPLY_Q(10) APPLY_Q(11)                    \
            APPLY_Q(12) APPLY_Q(13) APPLY_Q(14) APPLY_Q(15)                    \
            acc &= __shfl_xor(acc, 16, 64);                                    \
            acc &= __shfl_xor(acc, 32, 64);                                    \
            kw &= acc;                                                         \
        }                                                                      \
    }

__global__ __launch_bounds__(64, 1) void k_scan(
    const uint64_t* __restrict__ M, const uint64_t* __restrict__ D,
    const uint32_t* __restrict__ Rnz, const uint64_t* __restrict__ keepw,
    const float* __restrict__ outs, const float* __restrict__ outc,
    const float* __restrict__ outb, float* __restrict__ out)
{
    int b = blockIdx.x;
    int lane = threadIdx.x;          // one wave
    int p = (lane >> 4) & 3;         // replica 0..3
    int w = lane & 15;               // word index
    const uint64_t* Mb = M + (size_t)b * 1024 * 16;
    const uint64_t* Dp = D + (size_t)b * 1024;
    const uint32_t* Rp = Rnz + (size_t)b * 1024;

    uint64_t kw = keepw[(size_t)b * 16 + w];   // word w, replicated x4

    uint32_t f0  = Rp[0 * 64 + lane],  f1  = Rp[1 * 64 + lane];
    uint32_t f2  = Rp[2 * 64 + lane],  f3  = Rp[3 * 64 + lane];
    uint32_t f4  = Rp[4 * 64 + lane],  f5  = Rp[5 * 64 + lane];
    uint32_t f6  = Rp[6 * 64 + lane],  f7  = Rp[7 * 64 + lane];
    uint32_t f8  = Rp[8 * 64 + lane],  f9  = Rp[9 * 64 + lane];
    uint32_t f10 = Rp[10 * 64 + lane], f11 = Rp[11 * 64 + lane];
    uint32_t f12 = Rp[12 * 64 + lane], f13 = Rp[13 * 64 + lane];
    uint32_t f14 = Rp[14 * 64 + lane], f15 = Rp[15 * 64 + lane];
    uint64_t nz0  = __ballot(f0 != 0),  nz1  = __ballot(f1 != 0);
    uint64_t nz2  = __ballot(f2 != 0),  nz3  = __ballot(f3 != 0);
    uint64_t nz4  = __ballot(f4 != 0),  nz5  = __ballot(f5 != 0);
    uint64_t nz6  = __ballot(f6 != 0),  nz7  = __ballot(f7 != 0);
    uint64_t nz8  = __ballot(f8 != 0),  nz9  = __ballot(f9 != 0);
    uint64_t nz10 = __ballot(f10 != 0), nz11 = __ballot(f11 != 0);
    uint64_t nz12 = __ballot(f12 != 0), nz13 = __ballot(f13 != 0);
    uint64_t nz14 = __ballot(f14 != 0), nz15 = __ballot(f15 != 0);

    uint64_t C0,C1,C2,C3,C4,C5,C6,C7,C8,C9,C10,C11,C12,C13,C14,C15;

    STEPG(0)  STEPG(1)  STEPG(2)  STEPG(3)
    STEPG(4)  STEPG(5)  STEPG(6)  STEPG(7)
    STEPG(8)  STEPG(9)  STEPG(10) STEPG(11)
    STEPG(12) STEPG(13) STEPG(14) STEPG(15)

#pragma unroll
    for (int t = 0; t < 16; ++t) {
        int j = t * 64 + lane;
        uint64_t kwt = rl64(kw, t);
        bool kp = (kwt >> lane) & 1ull;
        if (j < KTOP) {
            size_t ix = (size_t)b * 1024 + j;
            out[(size_t)b * KTOP + j] = kp ? outs[ix] : 0.0f;
            out[(size_t)NB * KTOP + (size_t)b * KTOP + j] = kp ? outc[ix] : 0.0f;
            float4 bb = kp ? ((const float4*)outb)[ix] : make_float4(0.f, 0.f, 0.f, 0.f);
            ((float4*)(out + 2 * (size_t)NB * KTOP))[(size_t)b * KTOP + j] = bb;
        }
    }
}

// ---------------- launch ----------------

extern "C" void kernel_launch(void* const* d_in, const int* in_sizes, int n_in,
                              void* d_out, int out_size, void* d_ws, size_t ws_size,
                              hipStream_t stream) {
    const float* cls[5];
    const float* cnt[5];
    const float* reg[5];
    for (int i = 0; i < 5; ++i) {
        cls[i] = (const float*)d_in[i];
        cnt[i] = (const float*)d_in[5 + i];
        reg[i] = (const float*)d_in[10 + i];
    }
    float* out = (float*)d_out;

    // ws layout (bytes); M reuses the packed region (packed dead after k_rankprep)
    char* ws = (char*)d_ws;
    uint64_t* packed  = (uint64_t*)(ws + 0);          // 8*16384*8   = 1,048,576
    uint64_t* M       = (uint64_t*)(ws + 0);          // 8*1024*16*8 = 1,048,576 (reuse)
    int*      classes = (int*)     (ws + 1048576);    // 426,976 -> ends 1,475,552
    uint32_t* ghist   = (uint32_t*)(ws + 1475552);    // 8*2048*4 = 65,536 -> 1,541,088
    double4*  rawbox  = (double4*) (ws + 1541088);    // 262,144 (32B aligned) -> 1,803,232
    float*    clsall  = (float*)   (ws + 1803232);    // 32,768 -> 1,836,000
    unsigned long long* pmaxE = (unsigned long long*)(ws + 1836000);  // 64 -> 1,836,064
    uint64_t* keepw   = (uint64_t*)(ws + 1836064);    // 1,024 -> 1,837,088
    uint64_t* D       = (uint64_t*)(ws + 1837088);    // 65,536 -> 1,902,624
    uint32_t* Rnz     = (uint32_t*)(ws + 1902624);    // 32,768 -> 1,935,392
    float*    outs    = (float*)   (ws + 1935392);    // 32,768 -> 1,968,160
    float*    outc    = (float*)   (ws + 1968160);    // 32,768 -> 2,000,928
    float*    outb    = (float*)   (ws + 2000928);    // 131,072 (16B aligned) -> 2,132,000

    // zero the global histogram (graph-capturable, stream-ordered)
    hipMemsetAsync(ghist, 0, (size_t)NB * 2048 * sizeof(uint32_t), stream);

    k_scores<<<(NB * PPAD) / 256, 256, 0, stream>>>(
        cls[0], cls[1], cls[2], cls[3], cls[4],
        cnt[0], cnt[1], cnt[2], cnt[3], cnt[4],
        packed, classes, ghist, keepw, pmaxE);

    k_rankprep<<<NB * 32, 256, 0, stream>>>(packed, ghist, classes,
                                            reg[0], reg[1], reg[2], reg[3], reg[4],
                                            rawbox, clsall, outs, outc, outb,
                                            keepw, pmaxE);

    k_mask<<<NB * 16, 256, 0, stream>>>(rawbox, clsall, pmaxE, M, D, Rnz);

    k_scan<<<NB, 64, 0, stream>>>(M, D, Rnz, keepw, outs, outc, outb, out);
}

// Round 14
// 85.249 us; speedup vs baseline: 1.2630x; 1.2609x over previous
//
#include <hip/hip_runtime.h>
#include <math.h>
#include <stdint.h>

#define NB 8
#define P_TOTAL 13343
#define NCLS 80
#define KTOP 1000
#define PPAD 16384
#define BCAP 256
#define D_SCORE_THR 0.05
#define D_IOU_THR 0.6

// ---------------- helpers ----------------

__device__ __forceinline__ double sig64(double x) {
    if (x >= 0.0) {
        double e = exp(-x);
        return 1.0 / (1.0 + e);
    } else {
        double e = exp(x);
        return e / (1.0 + e);
    }
}

// key = score bits (top 50) | (0x3FFF - idx): descending order => score desc, idx asc
__device__ __forceinline__ uint64_t pack_key(double s, int p) {
    uint64_t b = (uint64_t)__double_as_longlong(s);
    return (b & ~0x3FFFull) | (uint64_t)(0x3FFF - p);
}

__device__ __forceinline__ double key_score(uint64_t key) {
    return __longlong_as_double((long long)(key & ~0x3FFFull));
}

__device__ __forceinline__ int val_bin(double s) {
    int bin = (int)(s * 2048.0);
    return bin < 0 ? 0 : (bin > 2047 ? 2047 : bin);
}

__device__ __forceinline__ uint64_t rl64(uint64_t v, int l) {
    uint32_t lo = (uint32_t)__builtin_amdgcn_readlane((int)(uint32_t)v, l);
    uint32_t hi = (uint32_t)__builtin_amdgcn_readlane((int)(uint32_t)(v >> 32), l);
    return ((uint64_t)hi << 32) | lo;
}

// order-preserving double -> u64 encoding (for atomicMax)
__device__ __forceinline__ unsigned long long enc64(double x) {
    long long u = __double_as_longlong(x);
    return (unsigned long long)(u < 0 ? ~u : (u | 0x8000000000000000ll));
}
__device__ __forceinline__ double dec64(unsigned long long e) {
    long long u = (e >> 63) ? (long long)(e & 0x7FFFFFFFFFFFFFFFull) : ~(long long)e;
    return __longlong_as_double(u);
}

// ---------------- S0: scores/classes -> keys + hist + per-bin buckets -----------

__global__ __launch_bounds__(256) void k_scores(
    const float* __restrict__ c0, const float* __restrict__ c1, const float* __restrict__ c2,
    const float* __restrict__ c3, const float* __restrict__ c4,
    const float* __restrict__ n0, const float* __restrict__ n1, const float* __restrict__ n2,
    const float* __restrict__ n3, const float* __restrict__ n4,
    uint64_t* __restrict__ packed, int* __restrict__ classes,
    uint32_t* __restrict__ ghist, uint32_t* __restrict__ bcnt,
    uint64_t* __restrict__ bucket,
    uint64_t* __restrict__ keepw, unsigned long long* __restrict__ pmaxE)
{
    int tid = threadIdx.x;
    if (blockIdx.x == 0) {
        if (tid < 128) keepw[tid] = 0ull;
        else if (tid < 136) pmaxE[tid - 128] = 0ull;
    }

    int gid = blockIdx.x * 256 + tid;
    if (gid >= NB * PPAD) return;
    int b = gid >> 14;
    int p = gid & (PPAD - 1);
    if (p >= P_TOTAL) { packed[gid] = 0; return; }

    int base, hw;
    const float* cls;
    const float* cnt;
    if (p < 10000)      { base = 0;     hw = 10000; cls = c0; cnt = n0; }
    else if (p < 12500) { base = 10000; hw = 2500;  cls = c1; cnt = n1; }
    else if (p < 13125) { base = 12500; hw = 625;   cls = c2; cnt = n2; }
    else if (p < 13294) { base = 13125; hw = 169;   cls = c3; cnt = n3; }
    else                { base = 13294; hw = 49;    cls = c4; cnt = n4; }
    int yx = p - base;

    // argmax over 80 logits; two 40-chains for ILP; first-max ties preserved.
    const float* cp = cls + (size_t)b * NCLS * hw + yx;
    float m0 = -3.4e38f, m1 = -3.4e38f;
    int a0 = 0, a1 = 40;
    for (int c = 0; c < 40; ++c) {
        float v0 = cp[(size_t)c * hw];
        float v1 = cp[(size_t)(c + 40) * hw];
        if (v0 > m0) { m0 = v0; a0 = c; }
        if (v1 > m1) { m1 = v1; a1 = c + 40; }
    }
    float m = m0; int am = a0;
    if (m1 > m0) { m = m1; am = a1; }

    float cv = cnt[(size_t)b * hw + yx];
    double s = sqrt(sig64((double)m) * sig64((double)cv));

    uint64_t key = pack_key(s, p);
    packed[gid] = key;
    classes[(size_t)b * P_TOTAL + p] = am + 1;

    // bin from MASKED key score (consistent with all later bin computations)
    int bn = val_bin(key_score(key));
    atomicAdd(&ghist[b * 2048 + bn], 1u);
    uint32_t slot = atomicAdd(&bcnt[b * 2048 + bn], 1u);
    if (slot < BCAP)
        bucket[((size_t)b * 2048 + bn) * BCAP + slot] = key;
}

// ---------------- S1: analytic-rank select+prep (no key-array rescans) ----------
// 256 blocks (32/batch). Block g owns source slice [g*512,(g+1)*512). For each
// passer k: rank(k) = #{keys > k} = suffix-hist(bin(k)) + #{same-bin keys > k}
// (exact: higher masked-score bin => larger key; same bin => full u64 compare
// over the bin's bucket). Keys unique => rank bijects onto the exact
// (score desc, idx asc) sorted order; passer set is rank-downward-closed, so
// ranks 0..1023 are each written exactly once across blocks.

__global__ __launch_bounds__(256) void k_rankprep(
    const uint64_t* __restrict__ packed, const uint32_t* __restrict__ ghist,
    const uint32_t* __restrict__ bcnt, const uint64_t* __restrict__ bucket,
    const int* __restrict__ classes,
    const float* __restrict__ r0, const float* __restrict__ r1, const float* __restrict__ r2,
    const float* __restrict__ r3, const float* __restrict__ r4,
    double4* __restrict__ rawbox, float* __restrict__ clsall,
    float* __restrict__ outs, float* __restrict__ outc, float* __restrict__ outb,
    uint64_t* __restrict__ keepw, unsigned long long* __restrict__ pmaxE)
{
    __shared__ uint32_t lh[2048];
    __shared__ uint32_t chs[64];
    __shared__ uint32_t chsuf[64];   // strictly-above chunk suffix sums
    __shared__ uint64_t pass[512];
    __shared__ double redw[4];
    __shared__ int sB, sNP;
    int blk = blockIdx.x;
    int b = blk >> 5, g = blk & 31;
    int tid = threadIdx.x;
    int lane = tid & 63, wid = tid >> 6;
    const uint64_t* pk = packed + (size_t)b * PPAD;

    for (int t = tid; t < 2048; t += 256) lh[t] = ghist[b * 2048 + t];
    if (tid == 0) sNP = 0;
    __syncthreads();

    if (tid < 64) {
        uint32_t ss = 0;
        for (int i = 0; i < 32; ++i) ss += lh[tid * 32 + i];
        chs[tid] = ss;
    }
    __syncthreads();
    if (wid == 0) {
        // reversed inclusive prefix P(l) = sum chs[63-l .. 63]
        uint32_t v = chs[63 - lane];
        uint32_t P = v;
        for (int d = 1; d < 64; d <<= 1) {
            uint32_t u = __shfl_up(P, d, 64);
            if (lane >= d) P += u;
        }
        chsuf[63 - lane] = P - v;              // strictly above chunk 63-lane
        uint64_t bal = __ballot(P >= 1024u);
        int lstar = __builtin_ctzll(bal);
        int cstar = 63 - lstar;
        uint32_t Pst = (uint32_t)__shfl((int)P, lstar, 64);
        uint32_t C1c = Pst - chs[cstar];
        uint32_t w = (lane < 32) ? lh[cstar * 32 + 31 - lane] : 0u;
        uint32_t Q = w;
        for (int d = 1; d < 32; d <<= 1) {
            uint32_t u = __shfl_up(Q, d, 64);
            if (lane >= d) Q += u;
        }
        uint64_t bal2 = __ballot((lane < 32) && (C1c + Q >= 1024u));
        int l2 = __builtin_ctzll(bal2);
        if (lane == 0) sB = cstar * 32 + 31 - l2;
    }
    __syncthreads();
    int B = sB;

    // extract this block's slice passers (512 keys -> 2 iterations)
    int src0 = g * 512;
#pragma unroll
    for (int k = 0; k < 2; ++k) {
        uint64_t key = pk[src0 + tid + k * 256];
        bool pred = (key != 0ull) && (val_bin(key_score(key)) >= B);
        uint64_t bal = __ballot(pred);
        int bs = 0;
        if (lane == 0 && bal) bs = atomicAdd(&sNP, (int)__popcll(bal));
        bs = __shfl(bs, 0, 64);
        if (pred) pass[bs + __popcll(bal & ((1ull << lane) - 1ull))] = key;
    }
    __syncthreads();
    int np = sNP;

    // per-passer analytic rank + gather (one passer per thread)
    double lm = -1e300;
    if (tid < np) {
        uint64_t key = pass[tid];
        double s = key_score(key);
        int bin = val_bin(s);
        int c = bin >> 5;
        uint32_t rank = chsuf[c];
        for (int j = bin + 1; j < (c + 1) * 32; ++j) rank += lh[j];
        uint32_t bc = bcnt[b * 2048 + bin];
        if (bc <= BCAP) {
            const uint64_t* bk = bucket + ((size_t)b * 2048 + bin) * BCAP;
            for (uint32_t i = 0; i < bc; ++i) rank += (bk[i] > key) ? 1u : 0u;
        } else {
            // exact fallback (never taken for this data): scan whole batch
            for (int t2 = 0; t2 < PPAD; ++t2) {
                uint64_t k2 = pk[t2];
                if (k2 > key && val_bin(key_score(k2)) == bin) ++rank;
            }
        }

        if (rank < 1024u) {
            int idx = 0x3FFF - (int)(key & 0x3FFF);
            idx = idx < 0 ? 0 : (idx > P_TOTAL - 1 ? P_TOTAL - 1 : idx);

            int base2, w2, hw, st;
            const float* reg;
            if (idx < 10000)      { base2 = 0;     w2 = 100; hw = 10000; st = 8;   reg = r0; }
            else if (idx < 12500) { base2 = 10000; w2 = 50;  hw = 2500;  st = 16;  reg = r1; }
            else if (idx < 13125) { base2 = 12500; w2 = 25;  hw = 625;   st = 32;  reg = r2; }
            else if (idx < 13294) { base2 = 13125; w2 = 13;  hw = 169;   st = 64;  reg = r3; }
            else                  { base2 = 13294; w2 = 7;   hw = 49;    st = 128; reg = r4; }
            int yx = idx - base2;
            int y = yx / w2;
            int x = yx - y * w2;
            double sx = (double)(x * st + st / 2);
            double sy = (double)(y * st + st / 2);
            const float* rp = reg + (size_t)b * 4 * hw + yx;
            double x1 = sx - (double)rp[0];
            double y1 = sy - (double)rp[hw];
            double x2 = sx + (double)rp[2 * (size_t)hw];
            double y2 = sy + (double)rp[3 * (size_t)hw];
            int cv = classes[(size_t)b * P_TOTAL + idx];

            bool valid = (rank < KTOP) && (s >= D_SCORE_THR);
            size_t ix = (size_t)b * 1024 + rank;
            rawbox[ix] = make_double4(x1, y1, x2, y2);
            clsall[ix] = (float)cv;
            if (rank < KTOP) {
                outs[ix] = (float)s;
                outc[ix] = (float)cv;
                ((float4*)outb)[ix] = make_float4((float)x1, (float)y1,
                                                  (float)x2, (float)y2);
                // reference: max over where(valid, coords, 0.0)
                lm = valid ? fmax(fmax(x1, y1), fmax(x2, y2)) : 0.0;
            }
            if (valid)
                atomicOr((unsigned long long*)&keepw[(size_t)b * 16 + (rank >> 6)],
                         1ull << (rank & 63));
        }
    }

    // block fmax reduce (exact) -> one atomicMax per block
    for (int d = 1; d < 64; d <<= 1)
        lm = fmax(lm, __shfl_xor(lm, d, 64));
    if (lane == 0) redw[wid] = lm;
    __syncthreads();
    if (tid == 0) {
        double mm = fmax(fmax(redw[0], redw[1]), fmax(redw[2], redw[3]));
        atomicMax(&pmaxE[b], enc64(mm));
    }
}

// ---------------- S2: mask matrix from staged boxes (coalesced) -----------------

__global__ __launch_bounds__(256) void k_mask(
    const double4* __restrict__ rawbox, const float* __restrict__ clsall,
    const unsigned long long* __restrict__ pmaxE,
    uint64_t* __restrict__ M, uint64_t* __restrict__ D,
    uint32_t* __restrict__ Rnz)
{
    __shared__ double lx1[1024], ly1[1024], lx2[1024], ly2[1024], lar[1024];
    __shared__ float4 fbox[1024];
    __shared__ uint64_t ornz[4][64];
    int bid = blockIdx.x;
    int b = bid >> 4, rb = bid & 15;
    int tid = threadIdx.x;

    double offscale = dec64(pmaxE[b]) + 1.0;

    for (int t = tid; t < 1024; t += 256) {
        size_t ix = (size_t)b * 1024 + t;
        double4 rb4 = rawbox[ix];
        double o = (double)clsall[ix] * offscale;
        double ox1 = rb4.x + o, oy1 = rb4.y + o;
        double ox2 = rb4.z + o, oy2 = rb4.w + o;
        lx1[t] = ox1; ly1[t] = oy1; lx2[t] = ox2; ly2[t] = oy2;
        lar[t] = (ox2 - ox1 + 1.0) * (oy2 - oy1 + 1.0);
        fbox[t] = make_float4((float)ox1, (float)oy1, (float)ox2, (float)oy2);
    }
    __syncthreads();

    int ww = tid >> 6;
    int l  = tid & 63;
    int r  = rb * 64 + l;
    float4 fr = fbox[r];
    double rx1 = lx1[r], ry1 = ly1[r], rx2 = lx2[r], ry2 = ly2[r], ra = lar[r];
    int wbase = ww * 4;

    uint64_t bits0 = 0, bits1 = 0, bits2 = 0, bits3 = 0;

#define COLWORD(Q, BITS)                                                       \
    {                                                                          \
        int cb = (wbase + (Q)) * 64;                                           \
        if (cb + 63 > r) {                                                     \
            for (int kk = 0; kk < 64; ++kk) {                                  \
                int j = cb + kk;                                               \
                float4 fb = fbox[j];                                           \
                float xm = fminf(fb.z, fr.z) - fmaxf(fb.x, fr.x);              \
                float ym = fminf(fb.w, fr.w) - fmaxf(fb.y, fr.y);              \
                if (xm > -0.5f && ym > -0.5f) {                                \
                    double xmn = fmax(lx1[j], rx1);                            \
                    double ymn = fmax(ly1[j], ry1);                            \
                    double xmx = fmin(lx2[j], rx2);                            \
                    double ymx = fmin(ly2[j], ry2);                            \
                    double iw = xmx - xmn; iw = iw < 0.0 ? 0.0 : iw;           \
                    double ih = ymx - ymn; ih = ih < 0.0 ? 0.0 : ih;           \
                    double inter = iw * ih;                                    \
                    double iou = inter / (ra + lar[j] - inter);                \
                    BITS |= ((uint64_t)((j > r) && (iou > D_IOU_THR))) << kk;  \
                }                                                              \
            }                                                                  \
        }                                                                      \
    }

    COLWORD(0, bits0) COLWORD(1, bits1) COLWORD(2, bits2) COLWORD(3, bits3)
#undef COLWORD

    size_t mrow = ((size_t)b * 1024 + r) * 16 + wbase;
    M[mrow + 0] = bits0; M[mrow + 1] = bits1;
    M[mrow + 2] = bits2; M[mrow + 3] = bits3;

    if (ww == (rb >> 2)) {
        uint64_t db = (rb & 3) == 0 ? bits0 : (rb & 3) == 1 ? bits1
                    : (rb & 3) == 2 ? bits2 : bits3;
        D[((size_t)b * 16 + rb) * 64 + l] = db;
    }

    ornz[ww][l] = bits0 | bits1 | bits2 | bits3;
    __syncthreads();
    if (ww == 0) {
        uint64_t o = ornz[0][l] | ornz[1][l] | ornz[2][l] | ornz[3][l];
        Rnz[(size_t)b * 1024 + r] = (o != 0) ? 1u : 0u;
    }
}

// ---------------- S3: one-wave sparse scan ----------------

#define LOADC(G)                                                               \
    C0  = Mb[((size_t)(G) * 64 +  0 + p) * 16 + w];                            \
    C1  = Mb[((size_t)(G) * 64 +  4 + p) * 16 + w];                            \
    C2  = Mb[((size_t)(G) * 64 +  8 + p) * 16 + w];                            \
    C3  = Mb[((size_t)(G) * 64 + 12 + p) * 16 + w];                            \
    C4  = Mb[((size_t)(G) * 64 + 16 + p) * 16 + w];                            \
    C5  = Mb[((size_t)(G) * 64 + 20 + p) * 16 + w];                            \
    C6  = Mb[((size_t)(G) * 64 + 24 + p) * 16 + w];                            \
    C7  = Mb[((size_t)(G) * 64 + 28 + p) * 16 + w];                            \
    C8  = Mb[((size_t)(G) * 64 + 32 + p) * 16 + w];                            \
    C9  = Mb[((size_t)(G) * 64 + 36 + p) * 16 + w];                            \
    C10 = Mb[((size_t)(G) * 64 + 40 + p) * 16 + w];                            \
    C11 = Mb[((size_t)(G) * 64 + 44 + p) * 16 + w];                            \
    C12 = Mb[((size_t)(G) * 64 + 48 + p) * 16 + w];                            \
    C13 = Mb[((size_t)(G) * 64 + 52 + p) * 16 + w];                            \
    C14 = Mb[((size_t)(G) * 64 + 56 + p) * 16 + w];                            \
    C15 = Mb[((size_t)(G) * 64 + 60 + p) * 16 + w];

#define APPLY_Q(q)                                                             \
    {                                                                          \
        uint64_t t_ = (alive >> (4 * (q) + p)) & 1ull;                         \
        acc &= ~(C##q & (0ull - t_));                                          \
    }

#define STEPG(G)                                                               \
    {                                                                          \
        uint64_t kg = rl64(kw, (G));                                           \
        if (kg & nz##G) {                                                      \
            uint64_t dg = Dp[(size_t)(G) * 64 + lane];                         \
            LOADC(G)                                                           \
            uint64_t cur = kg, it = kg & nz##G;                                \
            while (it) {                                                       \
                int kk = __builtin_ctzll(it);                                  \
                uint64_t dk = rl64(dg, kk);                                    \
                cur &= ~dk;                                                    \
                it &= ~dk;                                                     \
                it &= it - 1ull;                                               \
            }                                                                  \
            uint64_t alive = cur;                                              \
            uint64_t acc = ~0ull;                                              \
            APPLY_Q(0)  APPLY_Q(1)  APPLY_Q(2)  APPLY_Q(3)                     \
            APPLY_Q(4)  APPLY_Q(5)  APPLY_Q(6)  APPLY_Q(7)                     \
            APPLY_Q(8)  APPLY_Q(9)  APPLY_Q(10) APPLY_Q(11)                    \
            APPLY_Q(12) APPLY_Q(13) APPLY_Q(14) APPLY_Q(15)                    \
            acc &= __shfl_xor(acc, 16, 64);                                    \
            acc &= __shfl_xor(acc, 32, 64);                                    \
            kw &= acc;                                                         \
        }                                                                      \
    }

__global__ __launch_bounds__(64, 1) void k_scan(
    const uint64_t* __restrict__ M, const uint64_t* __restrict__ D,
    const uint32_t* __restrict__ Rnz, const uint64_t* __restrict__ keepw,
    const float* __restrict__ outs, const float* __restrict__ outc,
    const float* __restrict__ outb, float* __restrict__ out)
{
    int b = blockIdx.x;
    int lane = threadIdx.x;          // one wave
    int p = (lane >> 4) & 3;         // replica 0..3
    int w = lane & 15;               // word index
    const uint64_t* Mb = M + (size_t)b * 1024 * 16;
    const uint64_t* Dp = D + (size_t)b * 1024;
    const uint32_t* Rp = Rnz + (size_t)b * 1024;

    uint64_t kw = keepw[(size_t)b * 16 + w];   // word w, replicated x4

    uint32_t f0  = Rp[0 * 64 + lane],  f1  = Rp[1 * 64 + lane];
    uint32_t f2  = Rp[2 * 64 + lane],  f3  = Rp[3 * 64 + lane];
    uint32_t f4  = Rp[4 * 64 + lane],  f5  = Rp[5 * 64 + lane];
    uint32_t f6  = Rp[6 * 64 + lane],  f7  = Rp[7 * 64 + lane];
    uint32_t f8  = Rp[8 * 64 + lane],  f9  = Rp[9 * 64 + lane];
    uint32_t f10 = Rp[10 * 64 + lane], f11 = Rp[11 * 64 + lane];
    uint32_t f12 = Rp[12 * 64 + lane], f13 = Rp[13 * 64 + lane];
    uint32_t f14 = Rp[14 * 64 + lane], f15 = Rp[15 * 64 + lane];
    uint64_t nz0  = __ballot(f0 != 0),  nz1  = __ballot(f1 != 0);
    uint64_t nz2  = __ballot(f2 != 0),  nz3  = __ballot(f3 != 0);
    uint64_t nz4  = __ballot(f4 != 0),  nz5  = __ballot(f5 != 0);
    uint64_t nz6  = __ballot(f6 != 0),  nz7  = __ballot(f7 != 0);
    uint64_t nz8  = __ballot(f8 != 0),  nz9  = __ballot(f9 != 0);
    uint64_t nz10 = __ballot(f10 != 0), nz11 = __ballot(f11 != 0);
    uint64_t nz12 = __ballot(f12 != 0), nz13 = __ballot(f13 != 0);
    uint64_t nz14 = __ballot(f14 != 0), nz15 = __ballot(f15 != 0);

    uint64_t C0,C1,C2,C3,C4,C5,C6,C7,C8,C9,C10,C11,C12,C13,C14,C15;

    STEPG(0)  STEPG(1)  STEPG(2)  STEPG(3)
    STEPG(4)  STEPG(5)  STEPG(6)  STEPG(7)
    STEPG(8)  STEPG(9)  STEPG(10) STEPG(11)
    STEPG(12) STEPG(13) STEPG(14) STEPG(15)

#pragma unroll
    for (int t = 0; t < 16; ++t) {
        int j = t * 64 + lane;
        uint64_t kwt = rl64(kw, t);
        bool kp = (kwt >> lane) & 1ull;
        if (j < KTOP) {
            size_t ix = (size_t)b * 1024 + j;
            out[(size_t)b * KTOP + j] = kp ? outs[ix] : 0.0f;
            out[(size_t)NB * KTOP + (size_t)b * KTOP + j] = kp ? outc[ix] : 0.0f;
            float4 bb = kp ? ((const float4*)outb)[ix] : make_float4(0.f, 0.f, 0.f, 0.f);
            ((float4*)(out + 2 * (size_t)NB * KTOP))[(size_t)b * KTOP + j] = bb;
        }
    }
}

// ---------------- launch ----------------

extern "C" void kernel_launch(void* const* d_in, const int* in_sizes, int n_in,
                              void* d_out, int out_size, void* d_ws, size_t ws_size,
                              hipStream_t stream) {
    const float* cls[5];
    const float* cnt[5];
    const float* reg[5];
    for (int i = 0; i < 5; ++i) {
        cls[i] = (const float*)d_in[i];
        cnt[i] = (const float*)d_in[5 + i];
        reg[i] = (const float*)d_in[10 + i];
    }
    float* out = (float*)d_out;

    // ws layout (bytes); M reuses the packed region (packed dead after k_rankprep)
    char* ws = (char*)d_ws;
    uint64_t* packed  = (uint64_t*)(ws + 0);          // 1,048,576
    uint64_t* M       = (uint64_t*)(ws + 0);          // 1,048,576 (reuse)
    int*      classes = (int*)     (ws + 1048576);    // 426,976 -> 1,475,552
    uint32_t* ghist   = (uint32_t*)(ws + 1475552);    // 65,536  -> 1,541,088
    uint32_t* bcnt    = (uint32_t*)(ws + 1541088);    // 65,536  -> 1,606,624
    uint64_t* bucket  = (uint64_t*)(ws + 1606624);    // 8*2048*256*8 = 33,554,432 -> 35,161,056
    double4*  rawbox  = (double4*) (ws + 35161056);   // 262,144 (32B aligned) -> 35,423,200
    float*    clsall  = (float*)   (ws + 35423200);   // 32,768 -> 35,455,968
    unsigned long long* pmaxE = (unsigned long long*)(ws + 35455968);  // 64 -> 35,456,032
    uint64_t* keepw   = (uint64_t*)(ws + 35456032);   // 1,024 -> 35,457,056
    uint64_t* D       = (uint64_t*)(ws + 35457056);   // 65,536 -> 35,522,592
    uint32_t* Rnz     = (uint32_t*)(ws + 35522592);   // 32,768 -> 35,555,360
    float*    outs    = (float*)   (ws + 35555360);   // 32,768 -> 35,588,128
    float*    outc    = (float*)   (ws + 35588128);   // 32,768 -> 35,620,896
    float*    outb    = (float*)   (ws + 35620896);   // 131,072 (16B aligned) -> 35,751,968

    // zero ghist + bcnt (contiguous 128 KB; graph-capturable, stream-ordered)
    hipMemsetAsync(ghist, 0, 131072, stream);

    k_scores<<<(NB * PPAD) / 256, 256, 0, stream>>>(
        cls[0], cls[1], cls[2], cls[3], cls[4],
        cnt[0], cnt[1], cnt[2], cnt[3], cnt[4],
        packed, classes, ghist, bcnt, bucket, keepw, pmaxE);

    k_rankprep<<<NB * 32, 256, 0, stream>>>(packed, ghist, bcnt, bucket, classes,
                                            reg[0], reg[1], reg[2], reg[3], reg[4],
                                            rawbox, clsall, outs, outc, outb,
                                            keepw, pmaxE);

    k_mask<<<NB * 16, 256, 0, stream>>>(rawbox, clsall, pmaxE, M, D, Rnz);

    k_scan<<<NB, 64, 0, stream>>>(M, D, Rnz, keepw, outs, outc, outb, out);
}